// Round 11
// baseline (174.542 us; speedup 1.0000x reference)
//
#include <hip/hip_runtime.h>
#include <math.h>

typedef __attribute__((ext_vector_type(8))) short short8;
typedef __attribute__((ext_vector_type(4))) float f32x4;

namespace {
constexpr int BATCH = 4096;
constexpr int SEQT  = 256;
constexpr int INSZ  = 24;
constexpr int H     = 40;
constexpr int NOUT  = 24;
constexpr int R     = 16;    // rows per block (2 cohorts x 8), grid = 256
constexpr int NT    = 512;   // 8 waves: per cohort 3 gate + 1 FC/stage

__device__ __forceinline__ unsigned short f2bf(float f) {
  unsigned int u = __float_as_uint(f);
  return (unsigned short)((u + 0x7FFFu + ((u >> 16) & 1u)) >> 16);  // RNE
}
__device__ __forceinline__ unsigned int pack2(float a, float b) {
  return (unsigned)f2bf(a) | ((unsigned)f2bf(b) << 16);
}
__device__ __forceinline__ unsigned short cvt_bf16(float f) {
  float r;
  asm("v_cvt_pk_bf16_f32 %0, %1, %2" : "=v"(r) : "v"(f), "v"(f));
  return (unsigned short)__float_as_uint(r);
}
__device__ __forceinline__ float4 ld4(const float* p) {
  return *reinterpret_cast<const float4*>(p);
}
__device__ __forceinline__ float sigm(float v) {
  return __builtin_amdgcn_rcpf(1.0f + __builtin_amdgcn_exp2f(v * -1.442695041f));
}
__device__ __forceinline__ float tanh_fast(float v) {
  return fmaf(2.0f,
              __builtin_amdgcn_rcpf(1.0f + __builtin_amdgcn_exp2f(v * -2.885390082f)),
              -1.0f);
}
}  // namespace

// Two 8-row cohorts per block, flag-synced (no s_barrier in the loop) so their
// phases drift and each SIMD interleaves one cohort's stalls with the other's
// issue. Cohort rows r(0..7) sit at A-rows ar=(r>>1)*4+(r&1) = {0,1,4,5,8,9,
// 12,13}; rows {2,3,6,7,10,11,14,15} are zeros written once -> every lane's
// acc[0..1] are real rows: gate math is 2 items/lane (half of R10), MFMA pads
// are multiplies-by-zero (matrix pipe ~6% busy, free).
// Ring: 4 slots/cohort of A(t)=[x(t) k0..23 | h(t-1) k24..63] bf16, swizzled.
// Protocol (per cohort): gflag += 1 per gate wave per step (after lgkm-drained
// h writes); fcflag = k+1 after FC-iter k's LDS reads+stage writes drained.
// gate step t waits gflag>=3t (h(t-1)) && fcflag>=max(t-1,0) (x(t) staged,
// WAR on slot (t+1)&3). FC iter k waits gflag>=3k, stages x(k+2), does FC(k-1).
__global__ __launch_bounds__(NT, 1) void gru_cohort(
    const float* __restrict__ x, const float* __restrict__ Wih,
    const float* __restrict__ Whh, const float* __restrict__ bih,
    const float* __restrict__ bhh, const float* __restrict__ Wfc,
    const float* __restrict__ bfc, float* __restrict__ out,
    float* __restrict__ hid) {
  __shared__ __align__(16) unsigned short ring[2 * 4 * 1024];  // 16 KB
  __shared__ int flags[8];  // [c*4+0]=gflag, [c*4+1]=fcflag

  const int tid  = threadIdx.x;
  const int l    = tid & 63;
  const int w    = tid >> 6;
  const int c    = w >> 2;        // cohort 0/1 (waves 0-3 / 4-7)
  const int role = w & 3;         // 0-2 gate tiles, 3 FC+stage
  const int lm   = l & 15;
  const int lq   = l >> 4;
  const int gb0  = blockIdx.x * R + c * 8;
  const int rbase = c * 4096;     // cohort ring base (ushort idx)

  // zero ring (zero-rows + h(-1)=0) and init flags
  reinterpret_cast<uint4*>(ring)[tid]       = make_uint4(0, 0, 0, 0);
  reinterpret_cast<uint4*>(ring)[tid + 512] = make_uint4(0, 0, 0, 0);
  if (tid < 8) flags[tid] = ((tid & 3) == 1) ? -1 : 0;

  volatile int* gfv = &flags[c * 4 + 0];
  volatile int* ffv = &flags[c * 4 + 1];

  const int aBase0 = ((lm * 64 + lq * 8)      ^ ((lm & 7) << 3));
  const int aBase1 = ((lm * 64 + lq * 8 + 32) ^ ((lm & 7) << 3));

  __syncthreads();  // only block-wide barrier: init visible

  if (role < 3) {
    // ================= gate waves =================
    const int u = role * 16 + lm;
    const bool gvalid = (u < H);
    short8 B[4][2];
    float bias[4];
#pragma unroll
    for (int z = 0; z < 4; ++z) {
#pragma unroll
      for (int kt = 0; kt < 2; ++kt) {
        short8 b;
#pragma unroll
        for (int j = 0; j < 8; ++j) {
          const int k = kt * 32 + lq * 8 + j;
          float v = 0.0f;
          if (gvalid) {
            if (z == 0)      v = (k < 24) ? Wih[u * 24 + k]          : Whh[u * 40 + (k - 24)];
            else if (z == 1) v = (k < 24) ? Wih[(40 + u) * 24 + k]   : Whh[(40 + u) * 40 + (k - 24)];
            else if (z == 2) v = (k < 24) ? Wih[(80 + u) * 24 + k]   : 0.0f;
            else             v = (k < 24) ? 0.0f                     : Whh[(80 + u) * 40 + (k - 24)];
          }
          b[j] = (short)f2bf(v);
        }
        B[z][kt] = b;
      }
    }
    bias[0] = gvalid ? bih[u] + bhh[u] : 0.0f;
    bias[1] = gvalid ? bih[40 + u] + bhh[40 + u] : 0.0f;
    bias[2] = gvalid ? bih[80 + u] : 0.0f;   // n input bias
    bias[3] = gvalid ? bhh[80 + u] : 0.0f;   // n hidden bias (scaled by r)
    float hold0 = 0.0f, hold1 = 0.0f;
    int aw0, aw1;
    {
      const int r0 = lq * 4 + 0, r1 = lq * 4 + 1;   // A-rows of real items
      aw0 = ((r0 * 64 + 24 + u) ^ ((r0 & 7) << 3));
      aw1 = ((r1 * 64 + 24 + u) ^ ((r1 & 7) << 3));
    }

    for (int t = 0; t < SEQT; ++t) {
      const int so = rbase + ((t & 3) << 10);
      const int sn = rbase + (((t + 1) & 3) << 10);
      const int ng = 3 * t;
      const int nf = (t >= 2) ? (t - 1) : 0;
      while (*gfv < ng || *ffv < nf) { }
      asm volatile("" ::: "memory");

      const short8 A0 = *reinterpret_cast<const short8*>(&ring[so + aBase0]);
      const short8 A1 = *reinterpret_cast<const short8*>(&ring[so + aBase1]);
      f32x4 ar = {bias[0], bias[0], bias[0], bias[0]};
      f32x4 az = {bias[1], bias[1], bias[1], bias[1]};
      f32x4 ax = {bias[2], bias[2], bias[2], bias[2]};
      f32x4 ah = {bias[3], bias[3], bias[3], bias[3]};
      ar = __builtin_amdgcn_mfma_f32_16x16x32_bf16(A0, B[0][0], ar, 0, 0, 0);
      az = __builtin_amdgcn_mfma_f32_16x16x32_bf16(A0, B[1][0], az, 0, 0, 0);
      ax = __builtin_amdgcn_mfma_f32_16x16x32_bf16(A0, B[2][0], ax, 0, 0, 0);
      ah = __builtin_amdgcn_mfma_f32_16x16x32_bf16(A0, B[3][0], ah, 0, 0, 0);
      ar = __builtin_amdgcn_mfma_f32_16x16x32_bf16(A1, B[0][1], ar, 0, 0, 0);
      az = __builtin_amdgcn_mfma_f32_16x16x32_bf16(A1, B[1][1], az, 0, 0, 0);
      ah = __builtin_amdgcn_mfma_f32_16x16x32_bf16(A1, B[3][1], ah, 0, 0, 0);
      // (nx kt=1 tile identically zero -> skipped; 7 MFMAs)

      {
        const float rr = sigm(ar[0]);
        const float zz = sigm(az[0]);
        const float nn = tanh_fast(fmaf(rr, ah[0], ax[0]));
        const float h  = fmaf(zz, hold0 - nn, nn);
        hold0 = h;
        if (gvalid) ring[sn + aw0] = cvt_bf16(h);
      }
      {
        const float rr = sigm(ar[1]);
        const float zz = sigm(az[1]);
        const float nn = tanh_fast(fmaf(rr, ah[1], ax[1]));
        const float h  = fmaf(zz, hold1 - nn, nn);
        hold1 = h;
        if (gvalid) ring[sn + aw1] = cvt_bf16(h);
      }
      asm volatile("" ::: "memory");
      asm volatile("s_waitcnt lgkmcnt(0)" ::: "memory");
      if (l == 0) atomicAdd(&flags[c * 4], 1);
    }

    if (gvalid) {
      hid[(size_t)(gb0 + lq * 2 + 0) * H + u] = hold0;
      hid[(size_t)(gb0 + lq * 2 + 1) * H + u] = hold1;
    }
  } else {
    // ================= FC + x-stage wave =================
    short8 F[2][2];
    float biasF[2];
#pragma unroll
    for (int f = 0; f < 2; ++f) {
      const int o = f * 16 + lm;
#pragma unroll
      for (int kt = 0; kt < 2; ++kt) {
        short8 b;
#pragma unroll
        for (int j = 0; j < 8; ++j) {
          const int k = kt * 32 + lq * 8 + j;
          const float v = (o < NOUT && k >= 24) ? Wfc[o * H + (k - 24)] : 0.0f;
          b[j] = (short)f2bf(v);
        }
        F[f][kt] = b;
      }
      biasF[f] = (o < NOUT) ? bfc[o] : 0.0f;
    }
    float* orow0 = out + ((size_t)(gb0 + lq * 2 + 0) * SEQT) * NOUT;
    float* orow1 = out + ((size_t)(gb0 + lq * 2 + 1) * SEQT) * NOUT;

    // x staging: 48 chunks (8 rows x 6 float4), lanes l<48
    const bool xvalid = (l < 48);
    const int xr = l / 6;                  // cohort row 0..7
    const int c4 = (l - xr * 6) * 4;
    const int ar_ = ((xr >> 1) * 4) + (xr & 1);   // A-row for real row xr
    const int xwOff = ((ar_ * 64 + c4) ^ ((ar_ & 7) << 3));
    const float* xp = xvalid ? (x + ((size_t)(gb0 + xr) * SEQT) * INSZ + c4) : nullptr;

    float4 xPe = make_float4(0, 0, 0, 0), xPo = make_float4(0, 0, 0, 0);
    if (xvalid) {  // prologue: stage x(0),x(1); prefetch x(2),x(3)
      const float4 v0 = ld4(xp);
      *reinterpret_cast<uint2*>(&ring[rbase + xwOff]) =
          make_uint2(pack2(v0.x, v0.y), pack2(v0.z, v0.w));
      const float4 v1 = ld4(xp + INSZ);
      *reinterpret_cast<uint2*>(&ring[rbase + 1024 + xwOff]) =
          make_uint2(pack2(v1.x, v1.y), pack2(v1.z, v1.w));
      xPe = ld4(xp + 2 * INSZ);
      xPo = ld4(xp + 3 * INSZ);
    }
    asm volatile("" ::: "memory");
    asm volatile("s_waitcnt lgkmcnt(0)" ::: "memory");
    if (l == 0) *ffv = 0;

#define FC_ITER(K, XR)                                                          \
  {                                                                             \
    const int ngf = 3 * (K);                                                    \
    while (*gfv < ngf) { }                                                      \
    asm volatile("" ::: "memory");                                              \
    if (xvalid && (K) + 2 <= SEQT - 1) {                                        \
      const int sx = rbase + ((((K) + 2) & 3) << 10);                           \
      *reinterpret_cast<uint2*>(&ring[sx + xwOff]) =                            \
          make_uint2(pack2(XR.x, XR.y), pack2(XR.z, XR.w));                     \
      if ((K) + 4 <= SEQT - 1) XR = ld4(xp + (size_t)((K) + 4) * INSZ);         \
    }                                                                           \
    short8 hA0, hA1;                                                            \
    if ((K) >= 1) {                                                             \
      const int so = rbase + (((K) & 3) << 10);                                 \
      hA0 = *reinterpret_cast<const short8*>(&ring[so + aBase0]);               \
      hA1 = *reinterpret_cast<const short8*>(&ring[so + aBase1]);               \
    }                                                                           \
    asm volatile("" ::: "memory");                                              \
    asm volatile("s_waitcnt lgkmcnt(0)" ::: "memory");                          \
    if (l == 0) *ffv = (K) + 1;                                                 \
    if ((K) >= 1) {                                                             \
      f32x4 f0 = {biasF[0], biasF[0], biasF[0], biasF[0]};                      \
      f32x4 f1 = {biasF[1], biasF[1], biasF[1], biasF[1]};                      \
      f0 = __builtin_amdgcn_mfma_f32_16x16x32_bf16(hA0, F[0][0], f0, 0, 0, 0);  \
      f1 = __builtin_amdgcn_mfma_f32_16x16x32_bf16(hA0, F[1][0], f1, 0, 0, 0);  \
      f0 = __builtin_amdgcn_mfma_f32_16x16x32_bf16(hA1, F[0][1], f0, 0, 0, 0);  \
      f1 = __builtin_amdgcn_mfma_f32_16x16x32_bf16(hA1, F[1][1], f1, 0, 0, 0);  \
      const size_t toff = (size_t)((K) - 1) * NOUT;                             \
      orow0[toff + lm] = sigm(f0[0]);                                           \
      orow1[toff + lm] = sigm(f0[1]);                                           \
      if (lm < 8) {                                                             \
        orow0[toff + 16 + lm] = sigm(f1[0]);                                    \
        orow1[toff + 16 + lm] = sigm(f1[1]);                                    \
      }                                                                         \
    }                                                                           \
  }

    for (int kk = 0; kk < SEQT; kk += 2) {
      FC_ITER(kk, xPe)
      FC_ITER(kk + 1, xPo)
    }
    FC_ITER(SEQT, xPe)   // k=256: FC for t=255 (no staging)
#undef FC_ITER
  }
}

extern "C" void kernel_launch(void* const* d_in, const int* in_sizes, int n_in,
                              void* d_out, int out_size, void* d_ws, size_t ws_size,
                              hipStream_t stream) {
  const float* x   = (const float*)d_in[0];
  const float* Wih = (const float*)d_in[1];
  const float* Whh = (const float*)d_in[2];
  const float* bih = (const float*)d_in[3];
  const float* bhh = (const float*)d_in[4];
  const float* Wfc = (const float*)d_in[5];
  const float* bfc = (const float*)d_in[6];
  float* out = (float*)d_out;
  float* hid = out + (size_t)BATCH * SEQT * NOUT;

  dim3 grid(BATCH / R);
  dim3 block(NT);
  hipLaunchKernelGGL(gru_cohort, grid, block, 0, stream,
                     x, Wih, Whh, bih, bhh, Wfc, bfc, out, hid);
}

// Round 12
// 122.421 us; speedup vs baseline: 1.4257x; 1.4257x over previous
//
#include <hip/hip_runtime.h>
#include <math.h>

typedef __attribute__((ext_vector_type(8))) short short8;
typedef __attribute__((ext_vector_type(4))) float f32x4;

namespace {
constexpr int BATCH = 4096;
constexpr int SEQT  = 256;
constexpr int INSZ  = 24;
constexpr int H     = 40;
constexpr int NOUT  = 24;
constexpr int R     = 8;     // rows per block, grid = 512 (2 independent blocks/CU)
constexpr int NT    = 256;   // 4 waves: 0-2 gate tiles, 3 = x-stage + FC(lagged)

__device__ __forceinline__ unsigned short f2bf(float f) {
  unsigned int u = __float_as_uint(f);
  return (unsigned short)((u + 0x7FFFu + ((u >> 16) & 1u)) >> 16);  // RNE
}
__device__ __forceinline__ unsigned short cvt_bf16(float f) {
  float r;
  asm("v_cvt_pk_bf16_f32 %0, %1, %2" : "=v"(r) : "v"(f), "v"(f));
  return (unsigned short)__float_as_uint(r);   // low 16 bits = bf16(f), RNE
}
__device__ __forceinline__ float4 ld4(const float* p) {
  return *reinterpret_cast<const float4*>(p);
}
// Native-rate transcendentals (v_exp_f32/v_rcp_f32) — avoids IEEE div sequence.
__device__ __forceinline__ float sigm(float v) {
  return __builtin_amdgcn_rcpf(1.0f + __builtin_amdgcn_exp2f(v * -1.442695041f));
}
__device__ __forceinline__ float tanh_fast(float v) {
  return fmaf(2.0f,
              __builtin_amdgcn_rcpf(1.0f + __builtin_amdgcn_exp2f(v * -2.885390082f)),
              -1.0f);
}
}  // namespace

// Raw barrier: drain only LDS ops; global loads/stores stay in flight.
#define BAR()                                              \
  asm volatile("s_waitcnt lgkmcnt(0)" ::: "memory");       \
  __builtin_amdgcn_s_barrier();                            \
  __builtin_amdgcn_sched_barrier(0);

// Two independent 8-row blocks per CU (grid=512): separate hardware barriers
// -> phases drift; one block's latency chain is hidden under the other's
// issue (R8 showed same-block lockstep waves cannot do this). R5's padding
// tax dodged by placing real rows at A-rows lq*4+{0,1} = {0,1,4,5,8,9,12,13}:
// every lane's acc[0..1] are real -> gate math 2 items/lane, per-CU VALU work
// identical to the single-block R10 kernel. Pad A-rows stay zero forever.
__global__ __launch_bounds__(NT) void gru_mfma4(
    const float* __restrict__ x, const float* __restrict__ Wih,
    const float* __restrict__ Whh, const float* __restrict__ bih,
    const float* __restrict__ bhh, const float* __restrict__ Wfc,
    const float* __restrict__ bfc, float* __restrict__ out,
    float* __restrict__ hid) {
  __shared__ __align__(16) unsigned short Abuf[2 * 1024];

  const int tid = threadIdx.x;
  const int l   = tid & 63;
  const int w   = tid >> 6;
  const int lm  = l & 15;
  const int lq  = l >> 4;
  const int gb0 = blockIdx.x * R;

  reinterpret_cast<uint4*>(Abuf)[tid] = make_uint4(0, 0, 0, 0);  // zero both buffers

  const int aBase0 = ((lm * 64 + lq * 8)      ^ ((lm & 7) << 3));
  const int aBase1 = ((lm * 64 + lq * 8 + 32) ^ ((lm & 7) << 3));

  // ---------------- gate role (waves 0..2) ----------------
  short8 B[4][2];
  float bias[4] = {0, 0, 0, 0};
  float hold[2] = {0, 0};
  int aw[2] = {0, 0};
  int u = 0;
  bool gvalid = false;
  if (w < 3) {
    u = w * 16 + lm;
    gvalid = (u < H);
#pragma unroll
    for (int z = 0; z < 4; ++z) {
#pragma unroll
      for (int kt = 0; kt < 2; ++kt) {
        short8 b;
#pragma unroll
        for (int j = 0; j < 8; ++j) {
          const int k = kt * 32 + lq * 8 + j;
          float v = 0.0f;
          if (gvalid) {
            if (z == 0)      v = (k < 24) ? Wih[u * 24 + k]          : Whh[u * 40 + (k - 24)];
            else if (z == 1) v = (k < 24) ? Wih[(40 + u) * 24 + k]   : Whh[(40 + u) * 40 + (k - 24)];
            else if (z == 2) v = (k < 24) ? Wih[(80 + u) * 24 + k]   : 0.0f;
            else             v = (k < 24) ? 0.0f                     : Whh[(80 + u) * 40 + (k - 24)];
          }
          b[j] = (short)f2bf(v);
        }
        B[z][kt] = b;
      }
    }
    if (gvalid) {
      bias[0] = bih[u] + bhh[u];
      bias[1] = bih[40 + u] + bhh[40 + u];
      bias[2] = bih[80 + u];           // n input bias
      bias[3] = bhh[80 + u];           // n hidden bias (scaled by r)
    }
#pragma unroll
    for (int i = 0; i < 2; ++i) {
      const int arow = lq * 4 + i;     // real rows live at acc rows {0,1}
      aw[i] = ((arow * 64 + 24 + u) ^ ((arow & 7) << 3));
    }
  }

  // ---------------- x-stage + FC role (wave 3) ----------------
  short8 F[2][2];
  float biasF[2] = {0, 0};
  float* orow[2] = {nullptr, nullptr};
  const float* xp0 = nullptr;
  int xw0 = 0;
  bool xv = false;
  float4 xA0 = make_float4(0, 0, 0, 0), xB0 = make_float4(0, 0, 0, 0);
  if (w == 3) {
#pragma unroll
    for (int f = 0; f < 2; ++f) {
      const int o = f * 16 + lm;
#pragma unroll
      for (int kt = 0; kt < 2; ++kt) {
        short8 b;
#pragma unroll
        for (int j = 0; j < 8; ++j) {
          const int k = kt * 32 + lq * 8 + j;
          const float v = (o < NOUT && k >= 24) ? Wfc[o * H + (k - 24)] : 0.0f;
          b[j] = (short)f2bf(v);
        }
        F[f][kt] = b;
      }
      biasF[f] = (o < NOUT) ? bfc[o] : 0.0f;
    }
#pragma unroll
    for (int i = 0; i < 2; ++i)
      orow[i] = out + ((size_t)(gb0 + lq * 2 + i) * SEQT) * NOUT;

    // x staging: 48 float4 chunks (8 rows x 6), lanes l<48; row r -> A-row
    // ar = (r>>1)*4 + (r&1)
    xv = (l < 48);
    const int xr = l / 6, xc = (l - xr * 6) * 4;
    const int ar_ = ((xr >> 1) << 2) + (xr & 1);
    if (xv) xp0 = x + ((size_t)(gb0 + xr) * SEQT) * INSZ + xc;
    xw0 = ((ar_ * 64 + xc) ^ ((ar_ & 7) << 3));
  }

  __syncthreads();  // zero-init visible

  if (w == 3 && xv) {  // stage x(0) into buf0; prefetch x(1)->xA, x(2)->xB
    const float4 v0 = ld4(xp0);
    *reinterpret_cast<uint2*>(&Abuf[xw0]) = make_uint2(
        (unsigned)f2bf(v0.x) | ((unsigned)f2bf(v0.y) << 16),
        (unsigned)f2bf(v0.z) | ((unsigned)f2bf(v0.w) << 16));
    xA0 = ld4(xp0 + 1 * INSZ);
    xB0 = ld4(xp0 + 2 * INSZ);
  }
  __syncthreads();  // x(0) staged

// 7-MFMA gate step (nx kt=1 tile identically zero -> skipped); gate math on
// the 2 real acc rows only.
#define GATE_STEP(BO, NBO)                                                      \
  if (w < 3) {                                                                  \
    const short8 A0 = *reinterpret_cast<const short8*>(&Abuf[(BO) + aBase0]);   \
    const short8 A1 = *reinterpret_cast<const short8*>(&Abuf[(BO) + aBase1]);   \
    f32x4 ar = {bias[0], bias[0], bias[0], bias[0]};                            \
    f32x4 az = {bias[1], bias[1], bias[1], bias[1]};                            \
    f32x4 ax = {bias[2], bias[2], bias[2], bias[2]};                            \
    f32x4 ah = {bias[3], bias[3], bias[3], bias[3]};                            \
    ar = __builtin_amdgcn_mfma_f32_16x16x32_bf16(A0, B[0][0], ar, 0, 0, 0);     \
    az = __builtin_amdgcn_mfma_f32_16x16x32_bf16(A0, B[1][0], az, 0, 0, 0);     \
    ax = __builtin_amdgcn_mfma_f32_16x16x32_bf16(A0, B[2][0], ax, 0, 0, 0);     \
    ah = __builtin_amdgcn_mfma_f32_16x16x32_bf16(A0, B[3][0], ah, 0, 0, 0);     \
    ar = __builtin_amdgcn_mfma_f32_16x16x32_bf16(A1, B[0][1], ar, 0, 0, 0);     \
    az = __builtin_amdgcn_mfma_f32_16x16x32_bf16(A1, B[1][1], az, 0, 0, 0);     \
    ah = __builtin_amdgcn_mfma_f32_16x16x32_bf16(A1, B[3][1], ah, 0, 0, 0);     \
    _Pragma("unroll")                                                           \
    for (int i = 0; i < 2; ++i) {                                               \
      const float rr = sigm(ar[i]);                                             \
      const float zz = sigm(az[i]);                                             \
      const float nn = tanh_fast(fmaf(rr, ah[i], ax[i]));                       \
      const float h  = fmaf(zz, hold[i] - nn, nn);                              \
      hold[i] = h;                                                              \
      if (gvalid) Abuf[(NBO) + aw[i]] = cvt_bf16(h);                            \
    }                                                                           \
  }

// stage x(T) into buffer TBO from reg XS; reload XS <- x(T+2)
#define XSTAGE(T, TBO, XS)                                                      \
  if (xv) {                                                                     \
    if ((T) < SEQT) {                                                           \
      *reinterpret_cast<uint2*>(&Abuf[(TBO) + xw0]) = make_uint2(               \
          (unsigned)f2bf(XS.x) | ((unsigned)f2bf(XS.y) << 16),                  \
          (unsigned)f2bf(XS.z) | ((unsigned)f2bf(XS.w) << 16));                 \
    }                                                                           \
    if ((T) + 2 < SEQT) XS = ld4(xp0 + (size_t)((T) + 2) * INSZ);               \
  }

// FC for step T, reading buffer BO (= buffer holding h(T)); 2 real rows/lane
#define FC_STEP(T, BO)                                                          \
  {                                                                             \
    const short8 hA0 = *reinterpret_cast<const short8*>(&Abuf[(BO) + aBase0]);  \
    const short8 hA1 = *reinterpret_cast<const short8*>(&Abuf[(BO) + aBase1]);  \
    f32x4 f0 = {biasF[0], biasF[0], biasF[0], biasF[0]};                        \
    f32x4 f1 = {biasF[1], biasF[1], biasF[1], biasF[1]};                        \
    f0 = __builtin_amdgcn_mfma_f32_16x16x32_bf16(hA0, F[0][0], f0, 0, 0, 0);    \
    f1 = __builtin_amdgcn_mfma_f32_16x16x32_bf16(hA0, F[1][0], f1, 0, 0, 0);    \
    f0 = __builtin_amdgcn_mfma_f32_16x16x32_bf16(hA1, F[0][1], f0, 0, 0, 0);    \
    f1 = __builtin_amdgcn_mfma_f32_16x16x32_bf16(hA1, F[1][1], f1, 0, 0, 0);    \
    _Pragma("unroll")                                                           \
    for (int i = 0; i < 2; ++i) {                                               \
      orow[i][(size_t)(T) * NOUT + lm] = sigm(f0[i]);                           \
      if (lm < 8) orow[i][(size_t)(T) * NOUT + 16 + lm] = sigm(f1[i]);          \
    }                                                                           \
  }

  for (int tt = 0; tt < SEQT; tt += 2) {
    // ---- interval tt: bo=0, nbo=1024 ----
    GATE_STEP(0, 1024)
    if (w == 3) {
      XSTAGE(tt + 1, 1024, xA0)
      if (tt > 0) FC_STEP(tt - 1, 0)
    }
    BAR()
    // ---- interval tt+1: bo=1024, nbo=0 ----
    GATE_STEP(1024, 0)
    if (w == 3) {
      XSTAGE(tt + 2, 0, xB0)
      FC_STEP(tt, 1024)
    }
    BAR()
  }
  // epilogue: FC for the final step (h(255) lives in buf0)
  if (w == 3) FC_STEP(SEQT - 1, 0)

  // final hidden state from registers (2 real rows per lane)
  if (w < 3 && gvalid) {
#pragma unroll
    for (int i = 0; i < 2; ++i)
      hid[(size_t)(gb0 + lq * 2 + i) * H + u] = hold[i];
  }
}

extern "C" void kernel_launch(void* const* d_in, const int* in_sizes, int n_in,
                              void* d_out, int out_size, void* d_ws, size_t ws_size,
                              hipStream_t stream) {
  const float* x   = (const float*)d_in[0];
  const float* Wih = (const float*)d_in[1];
  const float* Whh = (const float*)d_in[2];
  const float* bih = (const float*)d_in[3];
  const float* bhh = (const float*)d_in[4];
  const float* Wfc = (const float*)d_in[5];
  const float* bfc = (const float*)d_in[6];
  float* out = (float*)d_out;
  float* hid = out + (size_t)BATCH * SEQT * NOUT;

  dim3 grid(BATCH / R);
  dim3 block(NT);
  hipLaunchKernelGGL(gru_mfma4, grid, block, 0, stream,
                     x, Wih, Whh, bih, bhh, Wfc, bfc, out, hid);
}